// Round 1
// baseline (696.664 us; speedup 1.0000x reference)
//
#include <hip/hip_runtime.h>
#include <hip/hip_bf16.h>
#include <math.h>

#define T_TOK 8192
#define E_EXP 8
#define D_DIM 1024
#define H_DIM 4096
#define K_CAP 1024

typedef __attribute__((ext_vector_type(8))) short short8;
typedef __attribute__((ext_vector_type(4))) float floatx4;
typedef __attribute__((ext_vector_type(16))) float floatx16;

typedef __attribute__((address_space(3))) unsigned int lds_u32_t;
typedef __attribute__((address_space(1))) unsigned int gbl_u32_t;
#define ASYNC_CP16(gptr, lptr) \
  __builtin_amdgcn_global_load_lds((gbl_u32_t*)(gptr), (lds_u32_t*)(lptr), 16, 0, 0)

static __device__ __forceinline__ unsigned int f2bf_u(float f) {
  union { float f; unsigned int u; } v; v.f = f;
  unsigned int r = v.u + 0x7FFF + ((v.u >> 16) & 1);
  return r >> 16;
}

// ---------------- zero output ----------------
__global__ __launch_bounds__(256) void zero_kernel(float* __restrict__ p, int n4) {
  int i = blockIdx.x * 256 + threadIdx.x;
  if (i < n4) ((floatx4*)p)[i] = (floatx4)0.0f;
}

// ---------------- transpose + convert: W [E][KD][ND] f32 -> WT [E][ND][KD] bf16 ----
template <int KD, int ND>
__global__ __launch_bounds__(256)
void transpose_kernel(const float* __restrict__ w, unsigned short* __restrict__ wt) {
  int e = blockIdx.z;
  int n0 = blockIdx.x * 64, k0 = blockIdx.y * 64;
  __shared__ float ts[64][65];
  int tid = threadIdx.x;
  int rr = tid >> 4;          // 0..15
  int cc = (tid & 15) * 4;    // 0..60
  const float* src = w + ((size_t)e * KD + k0 + rr) * ND + n0 + cc;
#pragma unroll
  for (int it = 0; it < 4; it++) {
    float4 v = *(const float4*)(src + (size_t)it * 16 * ND);
    int r = rr + it * 16;
    ts[r][cc + 0] = v.x; ts[r][cc + 1] = v.y; ts[r][cc + 2] = v.z; ts[r][cc + 3] = v.w;
  }
  __syncthreads();
  int n = tid >> 3;           // 0..31
  int k8 = (tid & 7) * 8;     // 0..56
#pragma unroll
  for (int it = 0; it < 2; it++) {
    int nn = n + it * 32;
    unsigned int u[4];
#pragma unroll
    for (int j = 0; j < 4; j++)
      u[j] = f2bf_u(ts[k8 + 2 * j][nn]) | (f2bf_u(ts[k8 + 2 * j + 1][nn]) << 16);
    *(uint4*)&wt[((size_t)e * ND + n0 + nn) * KD + k0 + k8] = *(uint4*)u;
  }
}

// ---------------- router: fp64 logits + softmax, keys; also emits x_bf ----------------
__global__ __launch_bounds__(256)
void router_kernel(const float* __restrict__ x, const float* __restrict__ rw,
                   float* __restrict__ logits_out, float* __restrict__ probs_ws,
                   unsigned long long* __restrict__ keys_ws,
                   unsigned short* __restrict__ x_bf) {
  int t = blockIdx.x;
  int tid = threadIdx.x;
  int lane = tid & 63, wid = tid >> 6;
  __shared__ float xs[D_DIM];
  __shared__ double dred[4 * E_EXP];
  __shared__ double dlog[E_EXP];
  for (int i = tid; i < D_DIM; i += 256) xs[i] = x[(size_t)t * D_DIM + i];
  __syncthreads();
  {  // fused x -> bf16
    int i4 = tid * 4;
    uint2 u;
    u.x = f2bf_u(xs[i4 + 0]) | (f2bf_u(xs[i4 + 1]) << 16);
    u.y = f2bf_u(xs[i4 + 2]) | (f2bf_u(xs[i4 + 3]) << 16);
    ((uint2*)(x_bf + (size_t)t * D_DIM))[tid] = u;
  }
#pragma unroll
  for (int e = 0; e < E_EXP; e++) {
    double s = 0.0;
#pragma unroll
    for (int i = 0; i < 4; i++) {
      int d = tid + i * 256;
      s += (double)xs[d] * (double)rw[e * D_DIM + d];
    }
#pragma unroll
    for (int off = 32; off > 0; off >>= 1) s += __shfl_down(s, off, 64);
    if (lane == 0) dred[wid * E_EXP + e] = s;
  }
  __syncthreads();
  if (tid < E_EXP) {
    double s = dred[tid] + dred[E_EXP + tid] + dred[2 * E_EXP + tid] + dred[3 * E_EXP + tid];
    dlog[tid] = s;
    logits_out[(size_t)t * E_EXP + tid] = (float)s;
  }
  __syncthreads();
  if (tid == 0) {
    double m = dlog[0];
#pragma unroll
    for (int e = 1; e < E_EXP; e++) m = dlog[e] > m ? dlog[e] : m;
    double ex[E_EXP], Z = 0.0;
#pragma unroll
    for (int e = 0; e < E_EXP; e++) { ex[e] = exp(dlog[e] - m); Z += ex[e]; }
#pragma unroll
    for (int e = 0; e < E_EXP; e++) {
      double p = ex[e] / Z;
      probs_ws[e * T_TOK + t] = (float)p;
      unsigned long long b = (unsigned long long)__double_as_longlong(p);
      keys_ws[e * T_TOK + t] = (b & ~8191ULL) | (unsigned long long)(8191 - t);
    }
  }
}

// ---------------- exact top-k by rank counting (256 blocks) ----------------
__global__ __launch_bounds__(256)
void topk_kernel(const unsigned long long* __restrict__ keys_ws,
                 const float* __restrict__ probs_ws,
                 int* __restrict__ sel_ws, float* __restrict__ wt_ws,
                 float* __restrict__ selout) {
  int e = blockIdx.x >> 5, seg = blockIdx.x & 31;
  int tid = threadIdx.x;
  const unsigned long long* keys = keys_ws + (size_t)e * T_TOK;
  __shared__ unsigned long long kbuf[2048];
  int t = seg * 256 + tid;
  unsigned long long own = keys[t];
  int rank = 0;
  for (int pass = 0; pass < 4; pass++) {
    __syncthreads();
    for (int j = tid; j < 2048; j += 256) kbuf[j] = keys[pass * 2048 + j];
    __syncthreads();
#pragma unroll 8
    for (int j = 0; j < 2048; j++) rank += (kbuf[j] > own);
  }
  if (rank < K_CAP) {
    sel_ws[e * K_CAP + rank] = t;
    wt_ws[e * K_CAP + rank] = probs_ws[e * T_TOK + t];
    selout[e * K_CAP + rank] = (float)t;
  }
}

// =====================================================================
// GEMM core: 256x256 tile, BK=64, 8 waves (2x4), 32x32x16 MFMA.
// Double-buffered LDS (2 x 64KB), stage-before-compute (one barrier/K-tile).
// LDS layout per buffer: A at [0,32KB): planes (h*2+kk32) of [128 rows][32 shorts],
// B at [32KB,64KB) same. Bank-conflict XOR swizzle within each 8KB plane:
//   phys_byte = log_byte ^ (((log_byte>>7)&3)<<4)   (involution, 16B-preserving)
// Applied on the READ side; staging feeds global_load_lds's LINEAR dest from the
// inverse-swizzled global source (chunk' = chunk ^ ((chunk>>3)&3)) -- rule #21.
// =====================================================================
template <int MODE, int KDIM, int NDIM>
__device__ __forceinline__ void gemm_core(
    int e, int m0, int n0, int kbase, int kch, bool add_bias,
    const unsigned short* __restrict__ abase,
    const unsigned short* __restrict__ bt,
    const float* __restrict__ bias,
    const int* __restrict__ sel,
    const float* __restrict__ wt,
    unsigned short* __restrict__ hout,
    float* __restrict__ results) {
  __shared__ __align__(16) unsigned char smem[131072];  // 2 x 64KB
  int tid = threadIdx.x;
  int lane = tid & 63, w = tid >> 6;
  int wm = w >> 2, wn = w & 3;   // 2 x 4 wave grid; wave owns 128x64 of C

  // ---- staging address precompute: per thread 4 A-chunks + 4 B-chunks (16B each)
  const unsigned short* srcA[4];
  const unsigned short* srcB[4];
  int ldsA[4], ldsB[4];
#pragma unroll
  for (int j = 0; j < 4; ++j) {
    int c = j * 512 + tid;              // 0..2047 chunk id within A (or B) region
    int h = c >> 10;                    // row-half plane pair
    int kk32 = (c >> 9) & 1;            // k-half plane
    int cp = c & 511;                   // chunk within 8KB plane
    int cpp = cp ^ ((cp >> 3) & 3);     // inverse swizzle (involution)
    int row = cpp >> 2, cch = cpp & 3;  // row 0..127, 16B column chunk 0..3
    int trow = h * 128 + row;           // row within 256-tile
    int koff = kk32 * 32 + cch * 8;     // element offset within BK=64
    size_t arow;
    if (MODE == 1) arow = (size_t)sel[e * K_CAP + m0 + trow];
    else           arow = (size_t)e * K_CAP + m0 + trow;
    srcA[j] = abase + arow * KDIM + kbase + koff;
    srcB[j] = bt + ((size_t)e * NDIM + n0 + trow) * KDIM + kbase + koff;
    ldsA[j] = c * 16;
    ldsB[j] = 32768 + c * 16;
  }

  auto stage = [&](int b) {
    char* Lb = (char*)smem + b * 65536;
#pragma unroll
    for (int j = 0; j < 4; ++j) {
      ASYNC_CP16(srcA[j], Lb + ldsA[j]);
      ASYNC_CP16(srcB[j], Lb + ldsB[j]);
      srcA[j] += 64; srcB[j] += 64;
    }
  };

  floatx16 acc[4][2];
#pragma unroll
  for (int i = 0; i < 4; ++i)
#pragma unroll
    for (int j = 0; j < 2; ++j) acc[i][j] = (floatx16)0.0f;

  int rA = lane & 31;            // row/col within 32-frag
  int q16 = (lane >> 5) * 16;    // 16B half selector within 16-k group

  int NT = kch / 64;

  // prologue: stage K-tile 0 into buf 0
  stage(0);
  __syncthreads();   // drains vmcnt(0): tile 0 landed

  for (int kt = 0; kt < NT; ++kt) {
    // issue next tile's staging first -> overlaps with compute below
    if (kt + 1 < NT) stage((kt + 1) & 1);

    const char* Lb = (const char*)smem + (kt & 1) * 65536;
    const char* Aplane = Lb + wm * 16384;                 // A: planes (wm*2+kk32)*8KB
    const char* Bplane = Lb + 32768 + (wn >> 1) * 16384;  // B: planes ((wn>>1)*2+kk32)*8KB
#pragma unroll
    for (int half = 0; half < 2; ++half) {   // kk32: k 0-31 then 32-63
      const char* Ap = Aplane + half * 8192;
      const char* Bp = Bplane + half * 8192;
      short8 av[4][2], bv[2][2];
#pragma unroll
      for (int fm = 0; fm < 4; ++fm) {
        int r = fm * 32 + rA;
        int xr = ((r >> 1) & 3) << 4;
#pragma unroll
        for (int kk = 0; kk < 2; ++kk) {
          int off = (r * 64 + kk * 32 + q16) ^ xr;
          av[fm][kk] = *(const short8*)(Ap + off);
        }
      }
#pragma unroll
      for (int fn = 0; fn < 2; ++fn) {
        int r = (wn & 1) * 64 + fn * 32 + rA;
        int xr = ((r >> 1) & 3) << 4;
#pragma unroll
        for (int kk = 0; kk < 2; ++kk) {
          int off = (r * 64 + kk * 32 + q16) ^ xr;
          bv[fn][kk] = *(const short8*)(Bp + off);
        }
      }
#pragma unroll
      for (int kk = 0; kk < 2; ++kk)    // ascending k16 order (matches prev numerics)
#pragma unroll
        for (int fm = 0; fm < 4; ++fm)
#pragma unroll
          for (int fn = 0; fn < 2; ++fn)
            acc[fm][fn] = __builtin_amdgcn_mfma_f32_32x32x16_bf16(
                av[fm][kk], bv[fn][kk], acc[fm][fn], 0, 0, 0);
    }
    __syncthreads();  // drains vmcnt(0) (next tile landed) + all reads done
  }

  // ---- epilogue: 32x32 C/D layout: col=lane&31, row=(r&3)+8*(r>>2)+4*(lane>>5) ----
  int hi = lane >> 5;
#pragma unroll
  for (int fm = 0; fm < 4; ++fm) {
    if (MODE == 1) {
#pragma unroll
      for (int fn = 0; fn < 2; ++fn) {
        int col = n0 + wn * 64 + fn * 32 + rA;
        float bv_ = bias[e * NDIM + col];
#pragma unroll
        for (int r = 0; r < 16; ++r) {
          int m_l = wm * 128 + fm * 32 + (r & 3) + 8 * (r >> 2) + 4 * hi;
          float v = acc[fm][fn][r] + bv_;
          float gl = 0.5f * v * (1.0f + erff(v * 0.70710678118f));  // exact GELU
          hout[((size_t)e * K_CAP + m0 + m_l) * NDIM + col] = (unsigned short)f2bf_u(gl);
        }
      }
    } else {
      int toks[16]; float wgts[16];
#pragma unroll
      for (int r = 0; r < 16; ++r) {
        int m_l = wm * 128 + fm * 32 + (r & 3) + 8 * (r >> 2) + 4 * hi;
        toks[r] = sel[e * K_CAP + m0 + m_l];
        wgts[r] = wt[e * K_CAP + m0 + m_l];
      }
#pragma unroll
      for (int fn = 0; fn < 2; ++fn) {
        int col = n0 + wn * 64 + fn * 32 + rA;
        float bv_ = add_bias ? bias[e * NDIM + col] : 0.0f;
#pragma unroll
        for (int r = 0; r < 16; ++r) {
          float v = (acc[fm][fn][r] + bv_) * wgts[r];
          atomicAdd(&results[(size_t)toks[r] * D_DIM + col], v);
        }
      }
    }
  }
}

// GEMM1: H = gelu(Xg @ W1 + b1).
__global__ __launch_bounds__(512, 2)
void moe_gemm1(const unsigned short* __restrict__ x_bf,
               const unsigned short* __restrict__ w1t,
               const float* __restrict__ b1,
               const int* __restrict__ sel,
               unsigned short* __restrict__ h) {
  gemm_core<1, D_DIM, H_DIM>(blockIdx.z, blockIdx.y * 256, blockIdx.x * 256,
                             0, D_DIM, true, x_bf, w1t, b1, sel, nullptr, h, nullptr);
}

// GEMM2: results += wt * (H @ W2 + b2). Split-K=2.
__global__ __launch_bounds__(512, 2)
void moe_gemm2(const unsigned short* __restrict__ h,
               const unsigned short* __restrict__ w2t,
               const float* __restrict__ b2,
               const int* __restrict__ sel,
               const float* __restrict__ wt,
               float* __restrict__ results) {
  int e = blockIdx.x;
  int rest = blockIdx.y;
  int s = rest & 1;
  int nt = (rest >> 1) & 3;
  int mt = rest >> 3;
  gemm_core<2, H_DIM, D_DIM>(e, mt * 256, nt * 256, s * (H_DIM / 2), H_DIM / 2,
                             s == 0, h, w2t, b2, sel, wt, nullptr, results);
}

extern "C" void kernel_launch(void* const* d_in, const int* in_sizes, int n_in,
                              void* d_out, int out_size, void* d_ws, size_t ws_size,
                              hipStream_t stream) {
  const float* x  = (const float*)d_in[0];
  const float* rw = (const float*)d_in[1];
  const float* w1 = (const float*)d_in[2];
  const float* b1 = (const float*)d_in[3];
  const float* w2 = (const float*)d_in[4];
  const float* b2 = (const float*)d_in[5];

  float* out_res = (float*)d_out;                      // [8192][1024] fp32
  float* out_log = out_res + (size_t)T_TOK * D_DIM;    // [8192][8] fp32
  float* out_sel = out_log + (size_t)T_TOK * E_EXP;    // [8][1024] token ids as float

  char* ws = (char*)d_ws;
  float* probs_ws = (float*)ws;                                      // 256KB
  unsigned long long* keys_ws = (unsigned long long*)(ws + 262144);  // 512KB
  int* sel_ws = (int*)(ws + 786432);                                 // 32KB
  float* wt_ws = (float*)(ws + 819200);                              // 32KB
  unsigned short* x_bf = (unsigned short*)(ws + 1048576);            // 16MB
  unsigned short* h_ws = (unsigned short*)(ws + 17825792);           // 64MB
  unsigned short* t_buf = (unsigned short*)(ws + 84934656);          // 64MB (w1t, then w2t)

  zero_kernel<<<(T_TOK * D_DIM / 4 + 255) / 256, 256, 0, stream>>>(out_res, T_TOK * D_DIM / 4);

  router_kernel<<<T_TOK, 256, 0, stream>>>(x, rw, out_log, probs_ws, keys_ws, x_bf);

  topk_kernel<<<256, 256, 0, stream>>>(keys_ws, probs_ws, sel_ws, wt_ws, out_sel);

  // w1 [E][D][H] -> w1t [E][H][D] bf16
  transpose_kernel<D_DIM, H_DIM><<<dim3(H_DIM / 64, D_DIM / 64, E_EXP), 256, 0, stream>>>(
      w1, t_buf);

  moe_gemm1<<<dim3(H_DIM / 256, K_CAP / 256, E_EXP), 512, 0, stream>>>(
      x_bf, t_buf, b1, sel_ws, h_ws);

  // w2 [E][H][D] -> w2t [E][D][H] bf16 (reuse t_buf)
  transpose_kernel<H_DIM, D_DIM><<<dim3(D_DIM / 64, H_DIM / 64, E_EXP), 256, 0, stream>>>(
      w2, t_buf);

  moe_gemm2<<<dim3(E_EXP, 32), 512, 0, stream>>>(
      h_ws, t_buf, b2, sel_ws, wt_ws, out_res);
}